// Round 1
// baseline (2169.581 us; speedup 1.0000x reference)
//
#include <hip/hip_runtime.h>
#include <stdint.h>

#define T_TOK 8192
#define DDIM 1024
#define NEXP 8
#define HDIM 3072

typedef __attribute__((ext_vector_type(8))) short bfrag;   // 8 bf16 in 4 VGPRs
typedef __attribute__((ext_vector_type(4))) float facc;    // 4 fp32 acc

__device__ __forceinline__ unsigned short f2bf(float f) {
  unsigned int u = __float_as_uint(f);
  u += 0x7FFFu + ((u >> 16) & 1u);      // round-to-nearest-even
  return (unsigned short)(u >> 16);
}

// ---------------- gating: one wave per token ----------------
__global__ __launch_bounds__(64) void gate_topk(
    const float* __restrict__ x, const float* __restrict__ gw,
    int* __restrict__ counts, int* __restrict__ tok_list,
    float* __restrict__ wt_list)
{
  const int t = blockIdx.x;
  const int lane = threadIdx.x;
  const float* xr = x + (size_t)t * DDIM;
  float p[NEXP];
#pragma unroll
  for (int e = 0; e < NEXP; ++e) p[e] = 0.f;
#pragma unroll 4
  for (int i = 0; i < DDIM / 64; ++i) {
    const int d = i * 64 + lane;
    const float xv = xr[d];
    const float4 g0 = *(const float4*)(gw + (size_t)d * NEXP);
    const float4 g1 = *(const float4*)(gw + (size_t)d * NEXP + 4);
    p[0] += xv * g0.x; p[1] += xv * g0.y; p[2] += xv * g0.z; p[3] += xv * g0.w;
    p[4] += xv * g1.x; p[5] += xv * g1.y; p[6] += xv * g1.z; p[7] += xv * g1.w;
  }
#pragma unroll
  for (int off = 32; off > 0; off >>= 1) {
#pragma unroll
    for (int e = 0; e < NEXP; ++e) p[e] += __shfl_down(p[e], off);
  }
  if (lane == 0) {
    int i1 = 0; float v1 = p[0];
#pragma unroll
    for (int e = 1; e < NEXP; ++e) if (p[e] > v1) { v1 = p[e]; i1 = e; }
    int i2 = -1; float v2 = -3.4e38f;
#pragma unroll
    for (int e = 0; e < NEXP; ++e) if (e != i1 && p[e] > v2) { v2 = p[e]; i2 = e; }
    // renormalized top-2 softmax weights: w0 = p1/(p1+p2) = sigmoid(l1-l2)
    const float w0 = 1.f / (1.f + __expf(v2 - v1));
    int q1 = atomicAdd(&counts[i1 * 32], 1);          // counters 128B apart
    tok_list[i1 * T_TOK + q1] = t;
    wt_list[i1 * T_TOK + q1] = w0;
    int q2 = atomicAdd(&counts[i2 * 32], 1);
    tok_list[i2 * T_TOK + q2] = t;
    wt_list[i2 * T_TOK + q2] = 1.f - w0;
  }
}

// ---------------- GEMM1: h = silu(Xg@w1) * (Xg@w3), bf16 out ----------------
// tile 64 tokens x 64 h-cols, 4 waves (wave w -> rows w*16..w*16+15), BK=32
__global__ __launch_bounds__(256) void moe_gemm1(
    const float* __restrict__ x, const float* __restrict__ w1,
    const float* __restrict__ w3, const int* __restrict__ counts,
    const int* __restrict__ tok_list, unsigned short* __restrict__ h_buf,
    int e)
{
  const int cnt = counts[e * 32];
  const int p0 = blockIdx.y * 64;
  if (p0 >= cnt) return;
  const int n0 = blockIdx.x * 64;

  __shared__ unsigned short As[64][40];    // [row][k], pad->40 keeps 16B align + ~2-way banks
  __shared__ unsigned short B1s[64][40];   // [n][k] (transposed for contiguous b-frag)
  __shared__ unsigned short B3s[64][40];

  const int tid = threadIdx.x;
  const int lane = tid & 63;
  const int wv = tid >> 6;

  const float* w1e = w1 + (size_t)e * DDIM * HDIM;
  const float* w3e = w3 + (size_t)e * DDIM * HDIM;
  const int* tl = tok_list + e * T_TOK;

  const int arow = tid >> 2;            // 0..63
  const int akseg = (tid & 3) * 8;      // 0,8,16,24
  int tok = -1;
  if (p0 + arow < cnt) tok = tl[p0 + arow];

  const int bk = tid >> 3;              // 0..31 (k row of B)
  const int bn4 = (tid & 7) * 4;        // n in 0..28 step 4

  facc acc1[4], acc3[4];
#pragma unroll
  for (int i = 0; i < 4; ++i)
#pragma unroll
    for (int j = 0; j < 4; ++j) { acc1[i][j] = 0.f; acc3[i][j] = 0.f; }

  const int mrow = wv * 16 + (lane & 15);
  const int kq = (lane >> 4) * 8;

  for (int k0 = 0; k0 < DDIM; k0 += 32) {
    { // stage A (gathered x rows, fp32 -> bf16)
      union { unsigned short s[8]; uint4 v; } tmp;
      if (tok >= 0) {
        const float* src = x + (size_t)tok * DDIM + k0 + akseg;
        const float4 f0 = *(const float4*)(src);
        const float4 f1 = *(const float4*)(src + 4);
        tmp.s[0]=f2bf(f0.x); tmp.s[1]=f2bf(f0.y); tmp.s[2]=f2bf(f0.z); tmp.s[3]=f2bf(f0.w);
        tmp.s[4]=f2bf(f1.x); tmp.s[5]=f2bf(f1.y); tmp.s[6]=f2bf(f1.z); tmp.s[7]=f2bf(f1.w);
      } else {
        tmp.v = make_uint4(0u, 0u, 0u, 0u);
      }
      *(uint4*)&As[arow][akseg] = tmp.v;
    }
    // stage B1/B3 transposed: two n-halves per thread
#pragma unroll
    for (int pass = 0; pass < 2; ++pass) {
      const int n = bn4 + pass * 32;
      const float4 f1v = *(const float4*)(w1e + (size_t)(k0 + bk) * HDIM + n0 + n);
      B1s[n + 0][bk] = f2bf(f1v.x);
      B1s[n + 1][bk] = f2bf(f1v.y);
      B1s[n + 2][bk] = f2bf(f1v.z);
      B1s[n + 3][bk] = f2bf(f1v.w);
      const float4 f3v = *(const float4*)(w3e + (size_t)(k0 + bk) * HDIM + n0 + n);
      B3s[n + 0][bk] = f2bf(f3v.x);
      B3s[n + 1][bk] = f2bf(f3v.y);
      B3s[n + 2][bk] = f2bf(f3v.z);
      B3s[n + 3][bk] = f2bf(f3v.w);
    }
    __syncthreads();
    const bfrag a = *(const bfrag*)&As[mrow][kq];
#pragma unroll
    for (int nt = 0; nt < 4; ++nt) {
      const bfrag b1 = *(const bfrag*)&B1s[nt * 16 + (lane & 15)][kq];
      acc1[nt] = __builtin_amdgcn_mfma_f32_16x16x32_bf16(a, b1, acc1[nt], 0, 0, 0);
      const bfrag b3 = *(const bfrag*)&B3s[nt * 16 + (lane & 15)][kq];
      acc3[nt] = __builtin_amdgcn_mfma_f32_16x16x32_bf16(a, b3, acc3[nt], 0, 0, 0);
    }
    __syncthreads();
  }
  // epilogue: h = silu(acc1)*acc3, store bf16
  const int rbase = p0 + wv * 16 + ((lane >> 4) * 4);
  const int cbase = n0 + (lane & 15);
#pragma unroll
  for (int r = 0; r < 4; ++r) {
    const int p = rbase + r;
    if (p < cnt) {
      unsigned short* dst = h_buf + (size_t)p * HDIM + cbase;
#pragma unroll
      for (int nt = 0; nt < 4; ++nt) {
        const float a1 = acc1[nt][r];
        const float a3 = acc3[nt][r];
        const float hv = a1 * a3 / (1.f + __expf(-a1));
        dst[nt * 16] = f2bf(hv);
      }
    }
  }
}

// ---------------- GEMM2: out[tok] += wt * (h @ w2) ----------------
__global__ __launch_bounds__(256) void moe_gemm2(
    const unsigned short* __restrict__ h_buf, const float* __restrict__ w2,
    const int* __restrict__ counts, const int* __restrict__ tok_list,
    const float* __restrict__ wt_list, float* __restrict__ out, int e)
{
  const int cnt = counts[e * 32];
  const int p0 = blockIdx.y * 64;
  if (p0 >= cnt) return;
  const int n0 = blockIdx.x * 64;

  __shared__ unsigned short As[64][40];
  __shared__ unsigned short Bs[64][40];

  const int tid = threadIdx.x;
  const int lane = tid & 63;
  const int wv = tid >> 6;

  const float* w2e = w2 + (size_t)e * HDIM * DDIM;
  const int* tl = tok_list + e * T_TOK;
  const float* wl = wt_list + e * T_TOK;

  const int arow = tid >> 2;
  const int akseg = (tid & 3) * 8;
  const bool avalid = (p0 + arow < cnt);

  const int bk = tid >> 3;
  const int bn4 = (tid & 7) * 4;

  facc acc[4];
#pragma unroll
  for (int i = 0; i < 4; ++i)
#pragma unroll
    for (int j = 0; j < 4; ++j) acc[i][j] = 0.f;

  const int mrow = wv * 16 + (lane & 15);
  const int kq = (lane >> 4) * 8;

  for (int k0 = 0; k0 < HDIM; k0 += 32) {
    if (avalid) {
      *(uint4*)&As[arow][akseg] =
          *(const uint4*)(h_buf + (size_t)(p0 + arow) * HDIM + k0 + akseg);
    } else {
      *(uint4*)&As[arow][akseg] = make_uint4(0u, 0u, 0u, 0u);
    }
#pragma unroll
    for (int pass = 0; pass < 2; ++pass) {
      const int n = bn4 + pass * 32;
      const float4 f = *(const float4*)(w2e + (size_t)(k0 + bk) * DDIM + n0 + n);
      Bs[n + 0][bk] = f2bf(f.x);
      Bs[n + 1][bk] = f2bf(f.y);
      Bs[n + 2][bk] = f2bf(f.z);
      Bs[n + 3][bk] = f2bf(f.w);
    }
    __syncthreads();
    const bfrag a = *(const bfrag*)&As[mrow][kq];
#pragma unroll
    for (int nt = 0; nt < 4; ++nt) {
      const bfrag b = *(const bfrag*)&Bs[nt * 16 + (lane & 15)][kq];
      acc[nt] = __builtin_amdgcn_mfma_f32_16x16x32_bf16(a, b, acc[nt], 0, 0, 0);
    }
    __syncthreads();
  }
  const int rbase = p0 + wv * 16 + ((lane >> 4) * 4);
  const int cbase = n0 + (lane & 15);
#pragma unroll
  for (int r = 0; r < 4; ++r) {
    const int p = rbase + r;
    if (p < cnt) {
      const int tok = tl[p];
      const float wt = wl[p];
      float* dst = out + (size_t)tok * DDIM + cbase;
#pragma unroll
      for (int nt = 0; nt < 4; ++nt) {
        atomicAdd(dst + nt * 16, acc[nt][r] * wt);
      }
    }
  }
}

__global__ void ws_too_small(float* out, int n) {
  int i = blockIdx.x * 256 + threadIdx.x;
  if (i < n) out[i] = 1.0e6f;   // sentinel: workspace shortage, not a math bug
}

extern "C" void kernel_launch(void* const* d_in, const int* in_sizes, int n_in,
                              void* d_out, int out_size, void* d_ws, size_t ws_size,
                              hipStream_t stream) {
  // setup_inputs dict order: x, gate_w, w1, w3, w2
  const float* x  = (const float*)d_in[0];
  const float* gw = (const float*)d_in[1];
  const float* w1 = (const float*)d_in[2];
  const float* w3 = (const float*)d_in[3];
  const float* w2 = (const float*)d_in[4];
  float* out = (float*)d_out;

  const size_t off_tok = 1024;                                   // counts: 8 ints, 128B apart
  const size_t off_wt  = off_tok + (size_t)NEXP * T_TOK * 4;     // tok_list
  const size_t off_h   = off_wt + (size_t)NEXP * T_TOK * 4;      // wt_list
  const size_t need    = off_h + (size_t)T_TOK * HDIM * 2;       // h (one expert, bf16)
  if (ws_size < need) {
    ws_too_small<<<(out_size + 255) / 256, 256, 0, stream>>>(out, out_size);
    return;
  }
  int* counts = (int*)d_ws;
  int* tok_list = (int*)((char*)d_ws + off_tok);
  float* wt_list = (float*)((char*)d_ws + off_wt);
  unsigned short* h_buf = (unsigned short*)((char*)d_ws + off_h);

  hipMemsetAsync(counts, 0, 1024, stream);
  hipMemsetAsync(out, 0, (size_t)out_size * sizeof(float), stream);

  gate_topk<<<T_TOK, 64, 0, stream>>>(x, gw, counts, tok_list, wt_list);
  for (int e = 0; e < NEXP; ++e) {
    moe_gemm1<<<dim3(HDIM / 64, T_TOK / 64), 256, 0, stream>>>(
        x, w1, w3, counts, tok_list, h_buf, e);
    moe_gemm2<<<dim3(DDIM / 64, T_TOK / 64), 256, 0, stream>>>(
        h_buf, w2, counts, tok_list, wt_list, out, e);
  }
}